// Round 1
// baseline (706.701 us; speedup 1.0000x reference)
//
#include <hip/hip_runtime.h>

#define N_NODES 50000
#define N_EDGES 800000
#define HID 128
#define SCAN_BLK 256

// ---------------- degree / norm ----------------
__global__ void deg_kernel(const int* __restrict__ src, const int* __restrict__ dst,
                           int* __restrict__ cnt_out, int* __restrict__ cnt_in) {
  int e = blockIdx.x * blockDim.x + threadIdx.x;
  if (e < N_EDGES) {
    atomicAdd(&cnt_out[src[e]], 1);
    atomicAdd(&cnt_in[dst[e]], 1);
  }
}

__global__ void norm_kernel(const int* __restrict__ cnt_out, const int* __restrict__ cnt_in,
                            float* __restrict__ norm_out, float* __restrict__ norm_in) {
  int v = blockIdx.x * blockDim.x + threadIdx.x;
  if (v < N_NODES) {
    int co = cnt_out[v]; if (co < 1) co = 1;
    int ci = cnt_in[v];  if (ci < 1) ci = 1;
    norm_out[v] = rsqrtf((float)co);
    norm_in[v]  = rsqrtf((float)ci);
  }
}

// ---------------- CSR build (hierarchical scan over cnt_in) ----------------
__global__ void scan_blocks_kernel(const int* __restrict__ cnt, int* __restrict__ ofs,
                                   int* __restrict__ blk_sums, int n) {
  __shared__ int s[SCAN_BLK];
  int t = threadIdx.x;
  int i = blockIdx.x * SCAN_BLK + t;
  int v = (i < n) ? cnt[i] : 0;
  s[t] = v;
  __syncthreads();
  for (int o = 1; o < SCAN_BLK; o <<= 1) {
    int x = (t >= o) ? s[t - o] : 0;
    __syncthreads();
    s[t] += x;
    __syncthreads();
  }
  if (i < n) ofs[i] = s[t] - v;          // exclusive, without block base
  if (t == SCAN_BLK - 1) blk_sums[blockIdx.x] = s[t];
}

__global__ void scan_sums_kernel(const int* __restrict__ blk_sums, int* __restrict__ blk_base,
                                 int nb) {
  __shared__ int s[SCAN_BLK];
  int t = threadIdx.x;
  int v = (t < nb) ? blk_sums[t] : 0;
  s[t] = v;
  __syncthreads();
  for (int o = 1; o < SCAN_BLK; o <<= 1) {
    int x = (t >= o) ? s[t - o] : 0;
    __syncthreads();
    s[t] += x;
    __syncthreads();
  }
  if (t < nb) blk_base[t] = s[t] - v;    // exclusive base per block
}

__global__ void add_base_kernel(int* __restrict__ ofs, const int* __restrict__ blk_base,
                                int* __restrict__ cursor, int n, int total) {
  int i = blockIdx.x * blockDim.x + threadIdx.x;
  if (i < n) {
    int r = ofs[i] + blk_base[i >> 8];
    ofs[i] = r;
    cursor[i] = r;
  }
  if (i == 0) ofs[n] = total;
}

__global__ void csr_fill_kernel(const int* __restrict__ src, const int* __restrict__ dst,
                                int* __restrict__ cursor, int* __restrict__ csr_src) {
  int e = blockIdx.x * blockDim.x + threadIdx.x;
  if (e < N_EDGES) {
    int p = atomicAdd(&cursor[dst[e]], 1);
    csr_src[p] = src[e];
  }
}

// ---------------- node embedding: h = node_feats[N,4] @ W[4,128] + b ----------------
__global__ void embed_kernel(const float* __restrict__ nf, const float* __restrict__ W,
                             const float* __restrict__ b, float* __restrict__ h) {
  int idx = blockIdx.x * blockDim.x + threadIdx.x;
  if (idx >= N_NODES * HID) return;
  int v = idx >> 7;
  int f = idx & (HID - 1);
  float acc = b[f];
#pragma unroll
  for (int k = 0; k < 4; ++k) acc += nf[v * 4 + k] * W[k * HID + f];
  h[idx] = acc;
}

// ---------------- GraphConv aggregate: one wave per node ----------------
// agg[v] = norm_in[v] * sum_{e: dst==v} h[src_e] * norm_out[src_e]
__global__ __launch_bounds__(256) void aggregate_kernel(
    const float* __restrict__ h, const int* __restrict__ row_ofs,
    const int* __restrict__ csr_src, const float* __restrict__ norm_out,
    const float* __restrict__ norm_in, float* __restrict__ agg) {
  int wave = (blockIdx.x * blockDim.x + threadIdx.x) >> 6;
  int lane = threadIdx.x & 63;
  if (wave >= N_NODES) return;
  int beg = row_ofs[wave], end = row_ofs[wave + 1];
  const float2* __restrict__ h2 = (const float2*)h;
  float2 acc = make_float2(0.f, 0.f);
  for (int i = beg; i < end; ++i) {
    int s = csr_src[i];             // wave-uniform broadcast load
    float w = norm_out[s];
    float2 hv = h2[s * 64 + lane];  // coalesced 512B row
    acc.x += hv.x * w;
    acc.y += hv.y * w;
  }
  float ni = norm_in[wave];
  ((float2*)agg)[wave * 64 + lane] = make_float2(acc.x * ni, acc.y * ni);
}

// ---------------- 128-col GEMM: out[v] = (relu?)(in[v] @ W + bias) ----------------
// block = 128 threads (one per col), 16 rows per block, row tile staged in LDS
template <bool RELU, bool BIAS>
__global__ __launch_bounds__(128) void gemm128_kernel(
    const float* __restrict__ in, const float* __restrict__ W,
    const float* __restrict__ bias, float* __restrict__ out, int nrows) {
  __shared__ float tile[16][HID];
  int f = threadIdx.x;
  int v0 = blockIdx.x * 16;
#pragma unroll
  for (int r = 0; r < 16; ++r) {
    int v = v0 + r;
    tile[r][f] = (v < nrows) ? in[v * HID + f] : 0.f;
  }
  __syncthreads();
  float acc[16];
  float b = BIAS ? bias[f] : 0.f;
#pragma unroll
  for (int r = 0; r < 16; ++r) acc[r] = b;
  for (int k = 0; k < HID; ++k) {
    float wk = W[k * HID + f];      // coalesced; hot in L1/L2
#pragma unroll
    for (int r = 0; r < 16; ++r) acc[r] += tile[r][k] * wk;  // tile[r][k] broadcast
  }
#pragma unroll
  for (int r = 0; r < 16; ++r) {
    int v = v0 + r;
    if (v < nrows) {
      float x = acc[r];
      if (RELU) x = fmaxf(x, 0.f);
      out[v * HID + f] = x;
    }
  }
}

// ---------------- edge output: one wave per edge ----------------
// out[e] = relu(y[src]+y[dst]+b1) . W2 + b2
__global__ __launch_bounds__(256) void edge_out_kernel(
    const int* __restrict__ src, const int* __restrict__ dst,
    const float* __restrict__ y, const float* __restrict__ b1,
    const float* __restrict__ w2, const float* __restrict__ b2,
    float* __restrict__ out) {
  int e = (blockIdx.x * blockDim.x + threadIdx.x) >> 6;
  int lane = threadIdx.x & 63;
  if (e >= N_EDGES) return;
  int s = src[e], d = dst[e];
  const float2* __restrict__ y2 = (const float2*)y;
  float2 a = y2[s * 64 + lane];
  float2 c = y2[d * 64 + lane];
  float2 bb = ((const float2*)b1)[lane];
  float2 w = ((const float2*)w2)[lane];
  float vx = fmaxf(a.x + c.x + bb.x, 0.f);
  float vy = fmaxf(a.y + c.y + bb.y, 0.f);
  float p = vx * w.x + vy * w.y;
#pragma unroll
  for (int off = 32; off > 0; off >>= 1) p += __shfl_down(p, off, 64);
  if (lane == 0) out[e] = p + b2[0];
}

extern "C" void kernel_launch(void* const* d_in, const int* in_sizes, int n_in,
                              void* d_out, int out_size, void* d_ws, size_t ws_size,
                              hipStream_t stream) {
  const float* node_feats = (const float*)d_in[1];
  const int*   src        = (const int*)d_in[2];
  const int*   dst        = (const int*)d_in[3];
  const float* W_nemb     = (const float*)d_in[6];
  const float* b_nemb     = (const float*)d_in[7];
  const float* gnn_W      = (const float*)d_in[8];   // [2,128,128]
  const float* gnn_b      = (const float*)d_in[9];   // [2,128]
  const float* out_W1     = (const float*)d_in[10];
  const float* out_b1     = (const float*)d_in[11];
  const float* out_W2     = (const float*)d_in[12];
  const float* out_b2     = (const float*)d_in[13];
  float* out = (float*)d_out;

  // workspace layout (256B-aligned carve-outs)
  size_t off = 0;
  char* base = (char*)d_ws;
  auto alloc = [&](size_t nbytes) -> char* {
    off = (off + 255) & ~(size_t)255;
    char* p = base + off;
    off += nbytes;
    return p;
  };
  int*   cnt_out  = (int*)alloc(N_NODES * 4);
  int*   cnt_in   = (int*)alloc(N_NODES * 4);
  float* norm_out = (float*)alloc(N_NODES * 4);
  float* norm_in  = (float*)alloc(N_NODES * 4);
  int*   row_ofs  = (int*)alloc((N_NODES + 1) * 4);
  int*   cursor   = (int*)alloc(N_NODES * 4);
  int*   blk_sums = (int*)alloc(SCAN_BLK * 4);
  int*   blk_base = (int*)alloc(SCAN_BLK * 4);
  int*   csr_src  = (int*)alloc((size_t)N_EDGES * 4);
  float* h_a      = (float*)alloc((size_t)N_NODES * HID * 4);
  float* h_b      = (float*)alloc((size_t)N_NODES * HID * 4);
  (void)ws_size; (void)n_in; (void)in_sizes; (void)out_size;

  const int nb_scan = (N_NODES + SCAN_BLK - 1) / SCAN_BLK;  // 196

  // degrees + norms
  hipMemsetAsync(cnt_out, 0, N_NODES * 4, stream);
  hipMemsetAsync(cnt_in, 0, N_NODES * 4, stream);
  deg_kernel<<<(N_EDGES + 255) / 256, 256, 0, stream>>>(src, dst, cnt_out, cnt_in);
  norm_kernel<<<nb_scan, 256, 0, stream>>>(cnt_out, cnt_in, norm_out, norm_in);

  // CSR by dst
  scan_blocks_kernel<<<nb_scan, SCAN_BLK, 0, stream>>>(cnt_in, row_ofs, blk_sums, N_NODES);
  scan_sums_kernel<<<1, SCAN_BLK, 0, stream>>>(blk_sums, blk_base, nb_scan);
  add_base_kernel<<<nb_scan, 256, 0, stream>>>(row_ofs, blk_base, cursor, N_NODES, N_EDGES);
  csr_fill_kernel<<<(N_EDGES + 255) / 256, 256, 0, stream>>>(src, dst, cursor, csr_src);

  // node embedding -> h_a
  embed_kernel<<<(N_NODES * HID + 255) / 256, 256, 0, stream>>>(node_feats, W_nemb, b_nemb, h_a);

  // 2 GraphConv layers: aggregate (h_a->h_b), gemm+relu (h_b->h_a)
  for (int l = 0; l < 2; ++l) {
    aggregate_kernel<<<(N_NODES * 64 + 255) / 256, 256, 0, stream>>>(
        h_a, row_ofs, csr_src, norm_out, norm_in, h_b);
    gemm128_kernel<true, true><<<(N_NODES + 15) / 16, 128, 0, stream>>>(
        h_b, gnn_W + (size_t)l * HID * HID, gnn_b + (size_t)l * HID, h_a, N_NODES);
  }

  // y = h @ out_W1 (no bias, no relu) -> h_b
  gemm128_kernel<false, false><<<(N_NODES + 15) / 16, 128, 0, stream>>>(
      h_a, out_W1, nullptr, h_b, N_NODES);

  // per-edge output
  edge_out_kernel<<<(N_EDGES * 64 + 255) / 256, 256, 0, stream>>>(
      src, dst, h_b, out_b1, out_W2, out_b2, out);
}

// Round 2
// 504.659 us; speedup vs baseline: 1.4004x; 1.4004x over previous
//
#include <hip/hip_runtime.h>

#define N_NODES 50000
#define N_EDGES 800000
#define HID 128
#define SCAN_BLK 256

// ---------------- degrees ----------------
__global__ void deg_kernel(const int* __restrict__ src, const int* __restrict__ dst,
                           int* __restrict__ cnt_out, int* __restrict__ cnt_in) {
  int e = blockIdx.x * blockDim.x + threadIdx.x;
  if (e < N_EDGES) {
    atomicAdd(&cnt_out[src[e]], 1);
    atomicAdd(&cnt_in[dst[e]], 1);
  }
}

__global__ void norm_kernel(const int* __restrict__ cnt_out, const int* __restrict__ cnt_in,
                            float* __restrict__ norm_out, float* __restrict__ norm_in) {
  int v = blockIdx.x * blockDim.x + threadIdx.x;
  if (v < N_NODES) {
    int co = cnt_out[v]; if (co < 1) co = 1;
    int ci = cnt_in[v];  if (ci < 1) ci = 1;
    norm_out[v] = rsqrtf((float)co);
    norm_in[v]  = rsqrtf((float)ci);
  }
}

// ---------------- CSR build (hierarchical scan over cnt_in) ----------------
__global__ void scan_blocks_kernel(const int* __restrict__ cnt, int* __restrict__ ofs,
                                   int* __restrict__ blk_sums, int n) {
  __shared__ int s[SCAN_BLK];
  int t = threadIdx.x;
  int i = blockIdx.x * SCAN_BLK + t;
  int v = (i < n) ? cnt[i] : 0;
  s[t] = v;
  __syncthreads();
  for (int o = 1; o < SCAN_BLK; o <<= 1) {
    int x = (t >= o) ? s[t - o] : 0;
    __syncthreads();
    s[t] += x;
    __syncthreads();
  }
  if (i < n) ofs[i] = s[t] - v;
  if (t == SCAN_BLK - 1) blk_sums[blockIdx.x] = s[t];
}

__global__ void scan_sums_kernel(const int* __restrict__ blk_sums, int* __restrict__ blk_base,
                                 int nb) {
  __shared__ int s[SCAN_BLK];
  int t = threadIdx.x;
  int v = (t < nb) ? blk_sums[t] : 0;
  s[t] = v;
  __syncthreads();
  for (int o = 1; o < SCAN_BLK; o <<= 1) {
    int x = (t >= o) ? s[t - o] : 0;
    __syncthreads();
    s[t] += x;
    __syncthreads();
  }
  if (t < nb) blk_base[t] = s[t] - v;
}

__global__ void add_base_kernel(int* __restrict__ ofs, const int* __restrict__ blk_base,
                                int* __restrict__ cursor, int n, int total) {
  int i = blockIdx.x * blockDim.x + threadIdx.x;
  if (i < n) {
    int r = ofs[i] + blk_base[i >> 8];
    ofs[i] = r;
    cursor[i] = r;
  }
  if (i == 0) ofs[n] = total;
}

// CSR slot = {src, edge_id}
__global__ void csr_fill_kernel(const int* __restrict__ src, const int* __restrict__ dst,
                                int* __restrict__ cursor, int2* __restrict__ csr) {
  int e = blockIdx.x * blockDim.x + threadIdx.x;
  if (e < N_EDGES) {
    int p = atomicAdd(&cursor[dst[e]], 1);
    csr[p] = make_int2(src[e], e);
  }
}

// ---------------- layer-1 fused aggregate on RAW 4-dim features ----------------
// agg4[v] = sum nf4[src]*norm_out[src];  sno[v] = sum norm_out[src]
__global__ void agg4_kernel(const float4* __restrict__ nf4, const float* __restrict__ no_,
                            const int2* __restrict__ csr, const int* __restrict__ row_ofs,
                            float4* __restrict__ agg4, float* __restrict__ sno) {
  int v = blockIdx.x * blockDim.x + threadIdx.x;
  if (v >= N_NODES) return;
  int beg = row_ofs[v], end = row_ofs[v + 1];
  float4 a = make_float4(0.f, 0.f, 0.f, 0.f);
  float sn = 0.f;
  int i = beg;
  for (; i + 1 < end; i += 2) {
    int s0 = csr[i].x, s1 = csr[i + 1].x;
    float w0 = no_[s0], w1 = no_[s1];
    float4 n0 = nf4[s0], n1 = nf4[s1];
    a.x += n0.x * w0 + n1.x * w1;
    a.y += n0.y * w0 + n1.y * w1;
    a.z += n0.z * w0 + n1.z * w1;
    a.w += n0.w * w0 + n1.w * w1;
    sn += w0 + w1;
  }
  if (i < end) {
    int s0 = csr[i].x;
    float w0 = no_[s0];
    float4 n0 = nf4[s0];
    a.x += n0.x * w0; a.y += n0.y * w0; a.z += n0.z * w0; a.w += n0.w * w0;
    sn += w0;
  }
  agg4[v] = a;
  sno[v] = sn;
}

// ---------------- layer-1 GEMM with fused 4->128 expansion ----------------
// tile = ((agg4 . Wn[:,f]) + bn[f]*sno) * ni;  out = relu(tile@W0 + b0) * no
__global__ __launch_bounds__(256) void gemm_l1_kernel(
    const float4* __restrict__ agg4, const float* __restrict__ sno,
    const float* __restrict__ ni_, const float* __restrict__ no_,
    const float* __restrict__ Wn, const float* __restrict__ bn,
    const float* __restrict__ W0, const float* __restrict__ b0,
    float* __restrict__ out, int nrows) {
  __shared__ float tile[32][HID];
  int f = threadIdx.x & 127, rg = threadIdx.x >> 7;
  int v0 = blockIdx.x * 32;
  float wn0 = Wn[f], wn1 = Wn[HID + f], wn2 = Wn[2 * HID + f], wn3 = Wn[3 * HID + f];
  float bnf = bn[f];
#pragma unroll
  for (int r = 0; r < 16; ++r) {
    int row = rg * 16 + r, v = v0 + row;
    float val = 0.f;
    if (v < nrows) {
      float4 a = agg4[v];
      val = (a.x * wn0 + a.y * wn1 + a.z * wn2 + a.w * wn3 + bnf * sno[v]) * ni_[v];
    }
    tile[row][f] = val;
  }
  __syncthreads();
  float acc[16];
  float b = b0[f];
#pragma unroll
  for (int r = 0; r < 16; ++r) acc[r] = b;
  for (int k = 0; k < HID; ++k) {
    float wk = W0[k * HID + f];
#pragma unroll
    for (int r = 0; r < 16; ++r) acc[r] += tile[rg * 16 + r][k] * wk;
  }
#pragma unroll
  for (int r = 0; r < 16; ++r) {
    int v = v0 + rg * 16 + r;
    if (v < nrows) out[(size_t)v * HID + f] = fmaxf(acc[r], 0.f) * no_[v];
  }
}

// ---------------- layer-2 aggregate: wave per node, 2-way unrolled gather ----------------
// agg[v] = ni[v] * sum h1s[src]   (h1s pre-scaled by norm_out)
__global__ __launch_bounds__(256) void aggregate_kernel(
    const float* __restrict__ h, const int* __restrict__ row_ofs,
    const int2* __restrict__ csr, const float* __restrict__ ni_,
    float* __restrict__ agg) {
  int v = (blockIdx.x * blockDim.x + threadIdx.x) >> 6;
  int lane = threadIdx.x & 63;
  if (v >= N_NODES) return;
  int beg = row_ofs[v], end = row_ofs[v + 1];
  const float2* __restrict__ h2 = (const float2*)h;
  float2 a0 = make_float2(0.f, 0.f), a1 = make_float2(0.f, 0.f);
  int i = beg;
  for (; i + 1 < end; i += 2) {
    int s0 = csr[i].x, s1 = csr[i + 1].x;
    float2 x0 = h2[(size_t)s0 * 64 + lane];
    float2 x1 = h2[(size_t)s1 * 64 + lane];
    a0.x += x0.x; a0.y += x0.y;
    a1.x += x1.x; a1.y += x1.y;
  }
  if (i < end) {
    int s0 = csr[i].x;
    float2 x0 = h2[(size_t)s0 * 64 + lane];
    a0.x += x0.x; a0.y += x0.y;
  }
  float n = ni_[v];
  ((float2*)agg)[(size_t)v * 64 + lane] = make_float2((a0.x + a1.x) * n, (a0.y + a1.y) * n);
}

// ---------------- fused layer-2 GEMM + output GEMM ----------------
// h2 = relu(in@W0 + b0);  y = h2@W1   (h2 stays in LDS)
__global__ __launch_bounds__(256) void gemm_dual_kernel(
    const float* __restrict__ in, const float* __restrict__ W0,
    const float* __restrict__ b0, const float* __restrict__ W1,
    float* __restrict__ out, int nrows) {
  __shared__ float tile[32][HID];
  int f = threadIdx.x & 127, rg = threadIdx.x >> 7;
  int v0 = blockIdx.x * 32;
#pragma unroll
  for (int r = 0; r < 16; ++r) {
    int row = rg * 16 + r, v = v0 + row;
    tile[row][f] = (v < nrows) ? in[(size_t)v * HID + f] : 0.f;
  }
  __syncthreads();
  float acc[16];
  float b = b0[f];
#pragma unroll
  for (int r = 0; r < 16; ++r) acc[r] = b;
  for (int k = 0; k < HID; ++k) {
    float wk = W0[k * HID + f];
#pragma unroll
    for (int r = 0; r < 16; ++r) acc[r] += tile[rg * 16 + r][k] * wk;
  }
  __syncthreads();
#pragma unroll
  for (int r = 0; r < 16; ++r) tile[rg * 16 + r][f] = fmaxf(acc[r], 0.f);
  __syncthreads();
#pragma unroll
  for (int r = 0; r < 16; ++r) acc[r] = 0.f;
  for (int k = 0; k < HID; ++k) {
    float wk = W1[k * HID + f];
#pragma unroll
    for (int r = 0; r < 16; ++r) acc[r] += tile[rg * 16 + r][k] * wk;
  }
#pragma unroll
  for (int r = 0; r < 16; ++r) {
    int v = v0 + rg * 16 + r;
    if (v < nrows) out[(size_t)v * HID + f] = acc[r];
  }
}

// ---------------- edge output, dst-grouped, 16 lanes per edge ----------------
// out[e] = relu(y[src]+y[dst]+b1) . W2 + b2
// lane l in group holds features [l*4..l*4+4) and [64+l*4..64+l*4+4)
__global__ __launch_bounds__(256) void edge_out_kernel(
    const int2* __restrict__ csr, const int* __restrict__ row_ofs,
    const float* __restrict__ y, const float* __restrict__ b1,
    const float* __restrict__ w2, const float* __restrict__ b2,
    float* __restrict__ out) {
  int v = (blockIdx.x * blockDim.x + threadIdx.x) >> 6;
  int lane = threadIdx.x & 63;
  if (v >= N_NODES) return;
  int beg = row_ofs[v], end = row_ofs[v + 1];
  if (beg >= end) return;
  int g = lane >> 4;   // 4 edge-groups per wave
  int l = lane & 15;
  const float4* __restrict__ y4 = (const float4*)y;
  const float4* __restrict__ b14 = (const float4*)b1;
  const float4* __restrict__ w24 = (const float4*)w2;
  float4 d0 = y4[(size_t)v * 32 + l];
  float4 d1 = y4[(size_t)v * 32 + 16 + l];
  float4 bb0 = b14[l], bb1 = b14[16 + l];
  d0.x += bb0.x; d0.y += bb0.y; d0.z += bb0.z; d0.w += bb0.w;
  d1.x += bb1.x; d1.y += bb1.y; d1.z += bb1.z; d1.w += bb1.w;
  float4 w0 = w24[l], w1 = w24[16 + l];
  float ob2 = b2[0];
  for (int i = beg; i < end; i += 4) {
    int idx = i + g;
    bool valid = idx < end;
    int2 se = csr[valid ? idx : beg];
    float4 a0 = y4[(size_t)se.x * 32 + l];
    float4 a1 = y4[(size_t)se.x * 32 + 16 + l];
    float p = fmaxf(a0.x + d0.x, 0.f) * w0.x + fmaxf(a0.y + d0.y, 0.f) * w0.y +
              fmaxf(a0.z + d0.z, 0.f) * w0.z + fmaxf(a0.w + d0.w, 0.f) * w0.w +
              fmaxf(a1.x + d1.x, 0.f) * w1.x + fmaxf(a1.y + d1.y, 0.f) * w1.y +
              fmaxf(a1.z + d1.z, 0.f) * w1.z + fmaxf(a1.w + d1.w, 0.f) * w1.w;
    p += __shfl_down(p, 8, 16);
    p += __shfl_down(p, 4, 16);
    p += __shfl_down(p, 2, 16);
    p += __shfl_down(p, 1, 16);
    if (l == 0 && valid) out[se.y] = p + ob2;
  }
}

extern "C" void kernel_launch(void* const* d_in, const int* in_sizes, int n_in,
                              void* d_out, int out_size, void* d_ws, size_t ws_size,
                              hipStream_t stream) {
  const float* node_feats = (const float*)d_in[1];
  const int*   src        = (const int*)d_in[2];
  const int*   dst        = (const int*)d_in[3];
  const float* W_nemb     = (const float*)d_in[6];
  const float* b_nemb     = (const float*)d_in[7];
  const float* gnn_W      = (const float*)d_in[8];   // [2,128,128]
  const float* gnn_b      = (const float*)d_in[9];   // [2,128]
  const float* out_W1     = (const float*)d_in[10];
  const float* out_b1     = (const float*)d_in[11];
  const float* out_W2     = (const float*)d_in[12];
  const float* out_b2     = (const float*)d_in[13];
  float* out = (float*)d_out;

  size_t off = 0;
  char* base = (char*)d_ws;
  auto alloc = [&](size_t nbytes) -> char* {
    off = (off + 255) & ~(size_t)255;
    char* p = base + off;
    off += nbytes;
    return p;
  };
  int*    cnt_out  = (int*)alloc(N_NODES * 4);
  int*    cnt_in   = (int*)alloc(N_NODES * 4);
  float*  norm_out = (float*)alloc(N_NODES * 4);
  float*  norm_in  = (float*)alloc(N_NODES * 4);
  int*    row_ofs  = (int*)alloc((N_NODES + 1) * 4);
  int*    cursor   = (int*)alloc(N_NODES * 4);
  int*    blk_sums = (int*)alloc(SCAN_BLK * 4);
  int*    blk_base = (int*)alloc(SCAN_BLK * 4);
  int2*   csr      = (int2*)alloc((size_t)N_EDGES * 8);
  float4* agg4     = (float4*)alloc((size_t)N_NODES * 16);
  float*  sno      = (float*)alloc(N_NODES * 4);
  float*  buf_a    = (float*)alloc((size_t)N_NODES * HID * 4);
  float*  buf_b    = (float*)alloc((size_t)N_NODES * HID * 4);
  (void)ws_size; (void)n_in; (void)in_sizes; (void)out_size;

  const int nb_scan = (N_NODES + SCAN_BLK - 1) / SCAN_BLK;  // 196

  hipMemsetAsync(cnt_out, 0, N_NODES * 4, stream);
  hipMemsetAsync(cnt_in, 0, N_NODES * 4, stream);
  deg_kernel<<<(N_EDGES + 255) / 256, 256, 0, stream>>>(src, dst, cnt_out, cnt_in);
  norm_kernel<<<nb_scan, 256, 0, stream>>>(cnt_out, cnt_in, norm_out, norm_in);

  scan_blocks_kernel<<<nb_scan, SCAN_BLK, 0, stream>>>(cnt_in, row_ofs, blk_sums, N_NODES);
  scan_sums_kernel<<<1, SCAN_BLK, 0, stream>>>(blk_sums, blk_base, nb_scan);
  add_base_kernel<<<nb_scan, 256, 0, stream>>>(row_ofs, blk_base, cursor, N_NODES, N_EDGES);
  csr_fill_kernel<<<(N_EDGES + 255) / 256, 256, 0, stream>>>(src, dst, cursor, csr);

  // layer 1 (fused algebraically): 4-dim aggregate + expand-GEMM -> buf_a = h1 * norm_out
  agg4_kernel<<<nb_scan, 256, 0, stream>>>((const float4*)node_feats, norm_out, csr, row_ofs,
                                           agg4, sno);
  gemm_l1_kernel<<<(N_NODES + 31) / 32, 256, 0, stream>>>(
      agg4, sno, norm_in, norm_out, W_nemb, b_nemb, gnn_W, gnn_b, buf_a, N_NODES);

  // layer 2 aggregate: buf_a -> buf_b (x norm_in)
  aggregate_kernel<<<(N_NODES * 64 + 255) / 256, 256, 0, stream>>>(
      buf_a, row_ofs, csr, norm_in, buf_b);

  // fused layer-2 GEMM + y GEMM: buf_b -> buf_a (= y)
  gemm_dual_kernel<<<(N_NODES + 31) / 32, 256, 0, stream>>>(
      buf_b, gnn_W + (size_t)HID * HID, gnn_b + HID, out_W1, buf_a, N_NODES);

  // per-edge output, dst-grouped
  edge_out_kernel<<<(N_NODES * 64 + 255) / 256, 256, 0, stream>>>(
      csr, row_ofs, buf_a, out_b1, out_W2, out_b2, out);
}

// Round 3
// 478.410 us; speedup vs baseline: 1.4772x; 1.0549x over previous
//
#include <hip/hip_runtime.h>

#define N_NODES 50000
#define N_EDGES 800000
#define HID 128
#define SCAN_BLK 256
#define AP 133   // padded row stride for As (bank-spread: 133%32=5)

// ---------------- degrees ----------------
__global__ void deg_kernel(const int* __restrict__ src, const int* __restrict__ dst,
                           int* __restrict__ cnt_out, int* __restrict__ cnt_in) {
  int e = blockIdx.x * blockDim.x + threadIdx.x;
  if (e < N_EDGES) {
    atomicAdd(&cnt_out[src[e]], 1);
    atomicAdd(&cnt_in[dst[e]], 1);
  }
}

__global__ void norm_kernel(const int* __restrict__ cnt_out, const int* __restrict__ cnt_in,
                            float* __restrict__ norm_out, float* __restrict__ norm_in) {
  int v = blockIdx.x * blockDim.x + threadIdx.x;
  if (v < N_NODES) {
    int co = cnt_out[v]; if (co < 1) co = 1;
    int ci = cnt_in[v];  if (ci < 1) ci = 1;
    norm_out[v] = rsqrtf((float)co);
    norm_in[v]  = rsqrtf((float)ci);
  }
}

// ---------------- CSR build ----------------
__global__ void scan_blocks_kernel(const int* __restrict__ cnt, int* __restrict__ ofs,
                                   int* __restrict__ blk_sums, int n) {
  __shared__ int s[SCAN_BLK];
  int t = threadIdx.x;
  int i = blockIdx.x * SCAN_BLK + t;
  int v = (i < n) ? cnt[i] : 0;
  s[t] = v;
  __syncthreads();
  for (int o = 1; o < SCAN_BLK; o <<= 1) {
    int x = (t >= o) ? s[t - o] : 0;
    __syncthreads();
    s[t] += x;
    __syncthreads();
  }
  if (i < n) ofs[i] = s[t] - v;
  if (t == SCAN_BLK - 1) blk_sums[blockIdx.x] = s[t];
}

__global__ void scan_sums_kernel(const int* __restrict__ blk_sums, int* __restrict__ blk_base,
                                 int nb) {
  __shared__ int s[SCAN_BLK];
  int t = threadIdx.x;
  int v = (t < nb) ? blk_sums[t] : 0;
  s[t] = v;
  __syncthreads();
  for (int o = 1; o < SCAN_BLK; o <<= 1) {
    int x = (t >= o) ? s[t - o] : 0;
    __syncthreads();
    s[t] += x;
    __syncthreads();
  }
  if (t < nb) blk_base[t] = s[t] - v;
}

__global__ void add_base_kernel(int* __restrict__ ofs, const int* __restrict__ blk_base,
                                int* __restrict__ cursor, int n, int total) {
  int i = blockIdx.x * blockDim.x + threadIdx.x;
  if (i < n) {
    int r = ofs[i] + blk_base[i >> 8];
    ofs[i] = r;
    cursor[i] = r;
  }
  if (i == 0) ofs[n] = total;
}

__global__ void csr_fill_kernel(const int* __restrict__ src, const int* __restrict__ dst,
                                int* __restrict__ cursor, int2* __restrict__ csr) {
  int e = blockIdx.x * blockDim.x + threadIdx.x;
  if (e < N_EDGES) {
    int p = atomicAdd(&cursor[dst[e]], 1);
    csr[p] = make_int2(src[e], e);
  }
}

// ---------------- layer-1 aggregate on RAW 4-dim features ----------------
__global__ void agg4_kernel(const float4* __restrict__ nf4, const float* __restrict__ no_,
                            const int2* __restrict__ csr, const int* __restrict__ row_ofs,
                            float4* __restrict__ agg4, float* __restrict__ sno) {
  int v = blockIdx.x * blockDim.x + threadIdx.x;
  if (v >= N_NODES) return;
  int beg = row_ofs[v], end = row_ofs[v + 1];
  float4 a = make_float4(0.f, 0.f, 0.f, 0.f);
  float sn = 0.f;
  int i = beg;
  for (; i + 1 < end; i += 2) {
    int s0 = csr[i].x, s1 = csr[i + 1].x;
    float w0 = no_[s0], w1 = no_[s1];
    float4 n0 = nf4[s0], n1 = nf4[s1];
    a.x += n0.x * w0 + n1.x * w1;
    a.y += n0.y * w0 + n1.y * w1;
    a.z += n0.z * w0 + n1.z * w1;
    a.w += n0.w * w0 + n1.w * w1;
    sn += w0 + w1;
  }
  if (i < end) {
    int s0 = csr[i].x;
    float w0 = no_[s0];
    float4 n0 = nf4[s0];
    a.x += n0.x * w0; a.y += n0.y * w0; a.z += n0.z * w0; a.w += n0.w * w0;
    sn += w0;
  }
  agg4[v] = a;
  sno[v] = sn;
}

// ---------------- layer-1: fused 4->128 expand + GEMM, register micro-tile ----------------
// At[k][r] = ((agg4[r].Wn[:,k]) + bn[k]*sno[r]) * ni[r]   (k-major in LDS)
// out[v,f] = relu(At^T @ W0 + b0) * no[v]
__global__ __launch_bounds__(256) void gemm_l1_kernel(
    const float4* __restrict__ agg4, const float* __restrict__ sno,
    const float* __restrict__ ni_, const float* __restrict__ no_,
    const float* __restrict__ Wn, const float* __restrict__ bn,
    const float* __restrict__ W0, const float* __restrict__ b0,
    float* __restrict__ out, int nrows) {
  __shared__ float At[HID * 64];      // 32 KB, k-major
  __shared__ float Wbuf[32 * HID];    // 16 KB
  int t = threadIdx.x;
  int v0 = blockIdx.x * 64;
  // stage At (computed): lane r = t&63, k-group kg = t>>6 covers 32 k's
  {
    int r = t & 63, kg = t >> 6;
    int v = v0 + r;
    float4 a = make_float4(0.f, 0.f, 0.f, 0.f);
    float sn = 0.f, nin = 0.f;
    if (v < nrows) { a = agg4[v]; sn = sno[v]; nin = ni_[v]; }
    for (int kk = 0; kk < 32; ++kk) {
      int k = kg * 32 + kk;  // wave-uniform
      float val = (a.x * Wn[k] + a.y * Wn[HID + k] + a.z * Wn[2 * HID + k] +
                   a.w * Wn[3 * HID + k] + bn[k] * sn) * nin;
      At[k * 64 + r] = val;
    }
  }
  int c0 = (t & 15) * 8, r0 = (t >> 4) * 4;
  float acc[4][8];
#pragma unroll
  for (int i = 0; i < 4; ++i)
#pragma unroll
    for (int j = 0; j < 8; ++j) acc[i][j] = 0.f;

  for (int kc = 0; kc < HID; kc += 32) {
    __syncthreads();
    { // stage W chunk
      const float4* wsrc = (const float4*)(W0 + kc * HID);
      float4* wdst = (float4*)Wbuf;
#pragma unroll
      for (int i = 0; i < 4; ++i) wdst[i * 256 + t] = wsrc[i * 256 + t];
    }
    __syncthreads();
#pragma unroll 4
    for (int kk = 0; kk < 32; ++kk) {
      float4 av = *(const float4*)&At[(kc + kk) * 64 + r0];
      float4 w0v = *(const float4*)&Wbuf[kk * HID + c0];
      float4 w1v = *(const float4*)&Wbuf[kk * HID + c0 + 4];
      float ar[4] = {av.x, av.y, av.z, av.w};
      float wv[8] = {w0v.x, w0v.y, w0v.z, w0v.w, w1v.x, w1v.y, w1v.z, w1v.w};
#pragma unroll
      for (int i = 0; i < 4; ++i)
#pragma unroll
        for (int j = 0; j < 8; ++j) acc[i][j] += ar[i] * wv[j];
    }
  }
  // epilogue: relu(acc+b0)*no
  float bb[8];
  {
    float4 b0v = *(const float4*)&b0[c0];
    float4 b1v = *(const float4*)&b0[c0 + 4];
    bb[0] = b0v.x; bb[1] = b0v.y; bb[2] = b0v.z; bb[3] = b0v.w;
    bb[4] = b1v.x; bb[5] = b1v.y; bb[6] = b1v.z; bb[7] = b1v.w;
  }
#pragma unroll
  for (int i = 0; i < 4; ++i) {
    int v = v0 + r0 + i;
    if (v < nrows) {
      float nov = no_[v];
      float4 o0, o1;
      o0.x = fmaxf(acc[i][0] + bb[0], 0.f) * nov;
      o0.y = fmaxf(acc[i][1] + bb[1], 0.f) * nov;
      o0.z = fmaxf(acc[i][2] + bb[2], 0.f) * nov;
      o0.w = fmaxf(acc[i][3] + bb[3], 0.f) * nov;
      o1.x = fmaxf(acc[i][4] + bb[4], 0.f) * nov;
      o1.y = fmaxf(acc[i][5] + bb[5], 0.f) * nov;
      o1.z = fmaxf(acc[i][6] + bb[6], 0.f) * nov;
      o1.w = fmaxf(acc[i][7] + bb[7], 0.f) * nov;
      *(float4*)&out[(size_t)v * HID + c0] = o0;
      *(float4*)&out[(size_t)v * HID + c0 + 4] = o1;
    }
  }
}

// ---------------- layer-2 aggregate: wave per node ----------------
__global__ __launch_bounds__(256) void aggregate_kernel(
    const float* __restrict__ h, const int* __restrict__ row_ofs,
    const int2* __restrict__ csr, const float* __restrict__ ni_,
    float* __restrict__ agg) {
  int v = (blockIdx.x * blockDim.x + threadIdx.x) >> 6;
  int lane = threadIdx.x & 63;
  if (v >= N_NODES) return;
  int beg = row_ofs[v], end = row_ofs[v + 1];
  const float2* __restrict__ h2 = (const float2*)h;
  float2 a0 = make_float2(0.f, 0.f), a1 = make_float2(0.f, 0.f);
  int i = beg;
  for (; i + 1 < end; i += 2) {
    int s0 = csr[i].x, s1 = csr[i + 1].x;
    float2 x0 = h2[(size_t)s0 * 64 + lane];
    float2 x1 = h2[(size_t)s1 * 64 + lane];
    a0.x += x0.x; a0.y += x0.y;
    a1.x += x1.x; a1.y += x1.y;
  }
  if (i < end) {
    int s0 = csr[i].x;
    float2 x0 = h2[(size_t)s0 * 64 + lane];
    a0.x += x0.x; a0.y += x0.y;
  }
  float n = ni_[v];
  ((float2*)agg)[(size_t)v * 64 + lane] = make_float2((a0.x + a1.x) * n, (a0.y + a1.y) * n);
}

// ---------------- fused layer-2 GEMM + output GEMM, register micro-tile ----------------
// T1 = relu(A@W0+b0) kept in LDS (overwrites A); y = T1@W1
__global__ __launch_bounds__(256) void gemm_dual_kernel(
    const float* __restrict__ in, const float* __restrict__ W0,
    const float* __restrict__ b0, const float* __restrict__ W1,
    float* __restrict__ out, int nrows) {
  __shared__ float As[64 * AP];       // ~33 KB, row-major padded
  __shared__ float Wbuf[32 * HID];    // 16 KB
  int t = threadIdx.x;
  int v0 = blockIdx.x * 64;
  // stage A rows (coalesced global float4 reads, scalar LDS writes due to pad)
  {
    const float4* in4 = (const float4*)in;
#pragma unroll
    for (int i = 0; i < 8; ++i) {
      int idx = i * 256 + t;
      int r = idx >> 5, q = idx & 31;
      int v = v0 + r;
      float4 val = make_float4(0.f, 0.f, 0.f, 0.f);
      if (v < nrows) val = in4[(size_t)v * 32 + q];
      float* p = &As[r * AP + q * 4];
      p[0] = val.x; p[1] = val.y; p[2] = val.z; p[3] = val.w;
    }
  }
  int c0 = (t & 15) * 8, r0 = (t >> 4) * 4;
  float acc[4][8];
#pragma unroll
  for (int i = 0; i < 4; ++i)
#pragma unroll
    for (int j = 0; j < 8; ++j) acc[i][j] = 0.f;

  // ---- GEMM 1: acc = A @ W0 ----
  for (int kc = 0; kc < HID; kc += 32) {
    __syncthreads();
    {
      const float4* wsrc = (const float4*)(W0 + kc * HID);
      float4* wdst = (float4*)Wbuf;
#pragma unroll
      for (int i = 0; i < 4; ++i) wdst[i * 256 + t] = wsrc[i * 256 + t];
    }
    __syncthreads();
#pragma unroll 4
    for (int kk = 0; kk < 32; ++kk) {
      int k = kc + kk;
      float ar[4];
#pragma unroll
      for (int i = 0; i < 4; ++i) ar[i] = As[(r0 + i) * AP + k];
      float4 w0v = *(const float4*)&Wbuf[kk * HID + c0];
      float4 w1v = *(const float4*)&Wbuf[kk * HID + c0 + 4];
      float wv[8] = {w0v.x, w0v.y, w0v.z, w0v.w, w1v.x, w1v.y, w1v.z, w1v.w};
#pragma unroll
      for (int i = 0; i < 4; ++i)
#pragma unroll
        for (int j = 0; j < 8; ++j) acc[i][j] += ar[i] * wv[j];
    }
  }
  __syncthreads();  // all GEMM-1 reads of As complete
  // T1 = relu(acc + b0) -> back into As
  {
    float bb[8];
    float4 b0v = *(const float4*)&b0[c0];
    float4 b1v = *(const float4*)&b0[c0 + 4];
    bb[0] = b0v.x; bb[1] = b0v.y; bb[2] = b0v.z; bb[3] = b0v.w;
    bb[4] = b1v.x; bb[5] = b1v.y; bb[6] = b1v.z; bb[7] = b1v.w;
#pragma unroll
    for (int i = 0; i < 4; ++i)
#pragma unroll
      for (int j = 0; j < 8; ++j) {
        As[(r0 + i) * AP + c0 + j] = fmaxf(acc[i][j] + bb[j], 0.f);
        acc[i][j] = 0.f;
      }
  }
  // ---- GEMM 2: acc = T1 @ W1 ----
  for (int kc = 0; kc < HID; kc += 32) {
    __syncthreads();
    {
      const float4* wsrc = (const float4*)(W1 + kc * HID);
      float4* wdst = (float4*)Wbuf;
#pragma unroll
      for (int i = 0; i < 4; ++i) wdst[i * 256 + t] = wsrc[i * 256 + t];
    }
    __syncthreads();
#pragma unroll 4
    for (int kk = 0; kk < 32; ++kk) {
      int k = kc + kk;
      float ar[4];
#pragma unroll
      for (int i = 0; i < 4; ++i) ar[i] = As[(r0 + i) * AP + k];
      float4 w0v = *(const float4*)&Wbuf[kk * HID + c0];
      float4 w1v = *(const float4*)&Wbuf[kk * HID + c0 + 4];
      float wv[8] = {w0v.x, w0v.y, w0v.z, w0v.w, w1v.x, w1v.y, w1v.z, w1v.w};
#pragma unroll
      for (int i = 0; i < 4; ++i)
#pragma unroll
        for (int j = 0; j < 8; ++j) acc[i][j] += ar[i] * wv[j];
    }
  }
  // store y
#pragma unroll
  for (int i = 0; i < 4; ++i) {
    int v = v0 + r0 + i;
    if (v < nrows) {
      float4 o0 = make_float4(acc[i][0], acc[i][1], acc[i][2], acc[i][3]);
      float4 o1 = make_float4(acc[i][4], acc[i][5], acc[i][6], acc[i][7]);
      *(float4*)&out[(size_t)v * HID + c0] = o0;
      *(float4*)&out[(size_t)v * HID + c0 + 4] = o1;
    }
  }
}

// ---------------- edge output, dst-grouped, 16 lanes per edge ----------------
__global__ __launch_bounds__(256) void edge_out_kernel(
    const int2* __restrict__ csr, const int* __restrict__ row_ofs,
    const float* __restrict__ y, const float* __restrict__ b1,
    const float* __restrict__ w2, const float* __restrict__ b2,
    float* __restrict__ out) {
  int v = (blockIdx.x * blockDim.x + threadIdx.x) >> 6;
  int lane = threadIdx.x & 63;
  if (v >= N_NODES) return;
  int beg = row_ofs[v], end = row_ofs[v + 1];
  if (beg >= end) return;
  int g = lane >> 4;
  int l = lane & 15;
  const float4* __restrict__ y4 = (const float4*)y;
  const float4* __restrict__ b14 = (const float4*)b1;
  const float4* __restrict__ w24 = (const float4*)w2;
  float4 d0 = y4[(size_t)v * 32 + l];
  float4 d1 = y4[(size_t)v * 32 + 16 + l];
  float4 bb0 = b14[l], bb1 = b14[16 + l];
  d0.x += bb0.x; d0.y += bb0.y; d0.z += bb0.z; d0.w += bb0.w;
  d1.x += bb1.x; d1.y += bb1.y; d1.z += bb1.z; d1.w += bb1.w;
  float4 w0 = w24[l], w1 = w24[16 + l];
  float ob2 = b2[0];
  for (int i = beg; i < end; i += 4) {
    int idx = i + g;
    bool valid = idx < end;
    int2 se = csr[valid ? idx : beg];
    float4 a0 = y4[(size_t)se.x * 32 + l];
    float4 a1 = y4[(size_t)se.x * 32 + 16 + l];
    float p = fmaxf(a0.x + d0.x, 0.f) * w0.x + fmaxf(a0.y + d0.y, 0.f) * w0.y +
              fmaxf(a0.z + d0.z, 0.f) * w0.z + fmaxf(a0.w + d0.w, 0.f) * w0.w +
              fmaxf(a1.x + d1.x, 0.f) * w1.x + fmaxf(a1.y + d1.y, 0.f) * w1.y +
              fmaxf(a1.z + d1.z, 0.f) * w1.z + fmaxf(a1.w + d1.w, 0.f) * w1.w;
    p += __shfl_down(p, 8, 16);
    p += __shfl_down(p, 4, 16);
    p += __shfl_down(p, 2, 16);
    p += __shfl_down(p, 1, 16);
    if (l == 0 && valid) out[se.y] = p + ob2;
  }
}

extern "C" void kernel_launch(void* const* d_in, const int* in_sizes, int n_in,
                              void* d_out, int out_size, void* d_ws, size_t ws_size,
                              hipStream_t stream) {
  const float* node_feats = (const float*)d_in[1];
  const int*   src        = (const int*)d_in[2];
  const int*   dst        = (const int*)d_in[3];
  const float* W_nemb     = (const float*)d_in[6];
  const float* b_nemb     = (const float*)d_in[7];
  const float* gnn_W      = (const float*)d_in[8];
  const float* gnn_b      = (const float*)d_in[9];
  const float* out_W1     = (const float*)d_in[10];
  const float* out_b1     = (const float*)d_in[11];
  const float* out_W2     = (const float*)d_in[12];
  const float* out_b2     = (const float*)d_in[13];
  float* out = (float*)d_out;

  size_t off = 0;
  char* base = (char*)d_ws;
  auto alloc = [&](size_t nbytes) -> char* {
    off = (off + 255) & ~(size_t)255;
    char* p = base + off;
    off += nbytes;
    return p;
  };
  int*    cnt_out  = (int*)alloc(N_NODES * 4);
  int*    cnt_in   = (int*)alloc(N_NODES * 4);
  float*  norm_out = (float*)alloc(N_NODES * 4);
  float*  norm_in  = (float*)alloc(N_NODES * 4);
  int*    row_ofs  = (int*)alloc((N_NODES + 1) * 4);
  int*    cursor   = (int*)alloc(N_NODES * 4);
  int*    blk_sums = (int*)alloc(SCAN_BLK * 4);
  int*    blk_base = (int*)alloc(SCAN_BLK * 4);
  int2*   csr      = (int2*)alloc((size_t)N_EDGES * 8);
  float4* agg4     = (float4*)alloc((size_t)N_NODES * 16);
  float*  sno      = (float*)alloc(N_NODES * 4);
  float*  buf_a    = (float*)alloc((size_t)N_NODES * HID * 4);
  float*  buf_b    = (float*)alloc((size_t)N_NODES * HID * 4);
  (void)ws_size; (void)n_in; (void)in_sizes; (void)out_size;

  const int nb_scan = (N_NODES + SCAN_BLK - 1) / SCAN_BLK;

  hipMemsetAsync(cnt_out, 0, N_NODES * 4, stream);
  hipMemsetAsync(cnt_in, 0, N_NODES * 4, stream);
  deg_kernel<<<(N_EDGES + 255) / 256, 256, 0, stream>>>(src, dst, cnt_out, cnt_in);
  norm_kernel<<<nb_scan, 256, 0, stream>>>(cnt_out, cnt_in, norm_out, norm_in);

  scan_blocks_kernel<<<nb_scan, SCAN_BLK, 0, stream>>>(cnt_in, row_ofs, blk_sums, N_NODES);
  scan_sums_kernel<<<1, SCAN_BLK, 0, stream>>>(blk_sums, blk_base, nb_scan);
  add_base_kernel<<<nb_scan, 256, 0, stream>>>(row_ofs, blk_base, cursor, N_NODES, N_EDGES);
  csr_fill_kernel<<<(N_EDGES + 255) / 256, 256, 0, stream>>>(src, dst, cursor, csr);

  agg4_kernel<<<nb_scan, 256, 0, stream>>>((const float4*)node_feats, norm_out, csr, row_ofs,
                                           agg4, sno);
  gemm_l1_kernel<<<(N_NODES + 63) / 64, 256, 0, stream>>>(
      agg4, sno, norm_in, norm_out, W_nemb, b_nemb, gnn_W, gnn_b, buf_a, N_NODES);

  aggregate_kernel<<<(N_NODES * 64 + 255) / 256, 256, 0, stream>>>(
      buf_a, row_ofs, csr, norm_in, buf_b);

  gemm_dual_kernel<<<(N_NODES + 63) / 64, 256, 0, stream>>>(
      buf_b, gnn_W + (size_t)HID * HID, gnn_b + HID, out_W1, buf_a, N_NODES);

  edge_out_kernel<<<(N_NODES * 64 + 255) / 256, 256, 0, stream>>>(
      csr, row_ofs, buf_a, out_b1, out_W2, out_b2, out);
}

// Round 4
// 457.131 us; speedup vs baseline: 1.5459x; 1.0465x over previous
//
#include <hip/hip_runtime.h>

#define N_NODES 50000
#define N_EDGES 800000
#define HID 128
#define SCAN_BLK 256
#define AP 133   // padded row stride for As (bank-spread: 133%32=5)

// ---------------- degrees ----------------
__global__ void deg_kernel(const int* __restrict__ src, const int* __restrict__ dst,
                           int* __restrict__ cnt_out, int* __restrict__ cnt_in) {
  int e = blockIdx.x * blockDim.x + threadIdx.x;
  if (e < N_EDGES) {
    atomicAdd(&cnt_out[src[e]], 1);
    atomicAdd(&cnt_in[dst[e]], 1);
  }
}

__global__ void norm_kernel(const int* __restrict__ cnt_out, const int* __restrict__ cnt_in,
                            float* __restrict__ norm_out, float* __restrict__ norm_in) {
  int v = blockIdx.x * blockDim.x + threadIdx.x;
  if (v < N_NODES) {
    int co = cnt_out[v]; if (co < 1) co = 1;
    int ci = cnt_in[v];  if (ci < 1) ci = 1;
    norm_out[v] = rsqrtf((float)co);
    norm_in[v]  = rsqrtf((float)ci);
  }
}

// ---------------- CSR build ----------------
__global__ void scan_blocks_kernel(const int* __restrict__ cnt, int* __restrict__ ofs,
                                   int* __restrict__ blk_sums, int n) {
  __shared__ int s[SCAN_BLK];
  int t = threadIdx.x;
  int i = blockIdx.x * SCAN_BLK + t;
  int v = (i < n) ? cnt[i] : 0;
  s[t] = v;
  __syncthreads();
  for (int o = 1; o < SCAN_BLK; o <<= 1) {
    int x = (t >= o) ? s[t - o] : 0;
    __syncthreads();
    s[t] += x;
    __syncthreads();
  }
  if (i < n) ofs[i] = s[t] - v;
  if (t == SCAN_BLK - 1) blk_sums[blockIdx.x] = s[t];
}

__global__ void scan_sums_kernel(const int* __restrict__ blk_sums, int* __restrict__ blk_base,
                                 int nb) {
  __shared__ int s[SCAN_BLK];
  int t = threadIdx.x;
  int v = (t < nb) ? blk_sums[t] : 0;
  s[t] = v;
  __syncthreads();
  for (int o = 1; o < SCAN_BLK; o <<= 1) {
    int x = (t >= o) ? s[t - o] : 0;
    __syncthreads();
    s[t] += x;
    __syncthreads();
  }
  if (t < nb) blk_base[t] = s[t] - v;
}

__global__ void add_base_kernel(int* __restrict__ ofs, const int* __restrict__ blk_base,
                                int* __restrict__ cursor, int n, int total) {
  int i = blockIdx.x * blockDim.x + threadIdx.x;
  if (i < n) {
    int r = ofs[i] + blk_base[i >> 8];
    ofs[i] = r;
    cursor[i] = r;
  }
  if (i == 0) ofs[n] = total;
}

__global__ void csr_fill_kernel(const int* __restrict__ src, const int* __restrict__ dst,
                                int* __restrict__ cursor, int* __restrict__ csr_src,
                                int* __restrict__ csr_eid) {
  int e = blockIdx.x * blockDim.x + threadIdx.x;
  if (e < N_EDGES) {
    int p = atomicAdd(&cursor[dst[e]], 1);
    csr_src[p] = src[e];
    csr_eid[p] = e;
  }
}

// ---------------- layer-1 aggregate on RAW 4-dim features ----------------
// 16-lane group per node (4 nodes/wave), lane-per-edge
__global__ __launch_bounds__(256) void agg4_kernel(
    const float4* __restrict__ nf4, const float* __restrict__ no_,
    const int* __restrict__ csr_src, const int* __restrict__ row_ofs,
    float4* __restrict__ agg4, float* __restrict__ sno) {
  int wid = (blockIdx.x * blockDim.x + threadIdx.x) >> 6;
  int lane = threadIdx.x & 63;
  int g = lane >> 4, l = lane & 15;
  int v = wid * 4 + g;
  if (v >= N_NODES) return;
  int beg = row_ofs[v], end = row_ofs[v + 1];
  float ax = 0.f, ay = 0.f, az = 0.f, aw = 0.f, sn = 0.f;
  for (int i = beg + l; i < end; i += 16) {
    int s = csr_src[i];
    float w = no_[s];
    float4 n = nf4[s];
    ax += n.x * w; ay += n.y * w; az += n.z * w; aw += n.w * w;
    sn += w;
  }
#pragma unroll
  for (int o = 1; o < 16; o <<= 1) {
    ax += __shfl_xor(ax, o, 16);
    ay += __shfl_xor(ay, o, 16);
    az += __shfl_xor(az, o, 16);
    aw += __shfl_xor(aw, o, 16);
    sn += __shfl_xor(sn, o, 16);
  }
  if (l == 0) {
    agg4[v] = make_float4(ax, ay, az, aw);
    sno[v] = sn;
  }
}

// ---------------- layer-1: fused 4->128 expand + GEMM, register micro-tile ----------------
__global__ __launch_bounds__(256) void gemm_l1_kernel(
    const float4* __restrict__ agg4, const float* __restrict__ sno,
    const float* __restrict__ ni_, const float* __restrict__ no_,
    const float* __restrict__ Wn, const float* __restrict__ bn,
    const float* __restrict__ W0, const float* __restrict__ b0,
    float* __restrict__ out, int nrows) {
  __shared__ float At[HID * 64];      // 32 KB, k-major
  __shared__ float Wbuf[32 * HID];    // 16 KB
  int t = threadIdx.x;
  int v0 = blockIdx.x * 64;
  {
    int r = t & 63, kg = t >> 6;
    int v = v0 + r;
    float4 a = make_float4(0.f, 0.f, 0.f, 0.f);
    float sn = 0.f, nin = 0.f;
    if (v < nrows) { a = agg4[v]; sn = sno[v]; nin = ni_[v]; }
    for (int kk = 0; kk < 32; ++kk) {
      int k = kg * 32 + kk;  // wave-uniform
      float val = (a.x * Wn[k] + a.y * Wn[HID + k] + a.z * Wn[2 * HID + k] +
                   a.w * Wn[3 * HID + k] + bn[k] * sn) * nin;
      At[k * 64 + r] = val;
    }
  }
  int c0 = (t & 15) * 8, r0 = (t >> 4) * 4;
  float acc[4][8];
#pragma unroll
  for (int i = 0; i < 4; ++i)
#pragma unroll
    for (int j = 0; j < 8; ++j) acc[i][j] = 0.f;

  for (int kc = 0; kc < HID; kc += 32) {
    __syncthreads();
    {
      const float4* wsrc = (const float4*)(W0 + kc * HID);
      float4* wdst = (float4*)Wbuf;
#pragma unroll
      for (int i = 0; i < 4; ++i) wdst[i * 256 + t] = wsrc[i * 256 + t];
    }
    __syncthreads();
#pragma unroll 4
    for (int kk = 0; kk < 32; ++kk) {
      float4 av = *(const float4*)&At[(kc + kk) * 64 + r0];
      float4 w0v = *(const float4*)&Wbuf[kk * HID + c0];
      float4 w1v = *(const float4*)&Wbuf[kk * HID + c0 + 4];
      float ar[4] = {av.x, av.y, av.z, av.w};
      float wv[8] = {w0v.x, w0v.y, w0v.z, w0v.w, w1v.x, w1v.y, w1v.z, w1v.w};
#pragma unroll
      for (int i = 0; i < 4; ++i)
#pragma unroll
        for (int j = 0; j < 8; ++j) acc[i][j] += ar[i] * wv[j];
    }
  }
  float bb[8];
  {
    float4 b0v = *(const float4*)&b0[c0];
    float4 b1v = *(const float4*)&b0[c0 + 4];
    bb[0] = b0v.x; bb[1] = b0v.y; bb[2] = b0v.z; bb[3] = b0v.w;
    bb[4] = b1v.x; bb[5] = b1v.y; bb[6] = b1v.z; bb[7] = b1v.w;
  }
#pragma unroll
  for (int i = 0; i < 4; ++i) {
    int v = v0 + r0 + i;
    if (v < nrows) {
      float nov = no_[v];
      float4 o0, o1;
      o0.x = fmaxf(acc[i][0] + bb[0], 0.f) * nov;
      o0.y = fmaxf(acc[i][1] + bb[1], 0.f) * nov;
      o0.z = fmaxf(acc[i][2] + bb[2], 0.f) * nov;
      o0.w = fmaxf(acc[i][3] + bb[3], 0.f) * nov;
      o1.x = fmaxf(acc[i][4] + bb[4], 0.f) * nov;
      o1.y = fmaxf(acc[i][5] + bb[5], 0.f) * nov;
      o1.z = fmaxf(acc[i][6] + bb[6], 0.f) * nov;
      o1.w = fmaxf(acc[i][7] + bb[7], 0.f) * nov;
      *(float4*)&out[(size_t)v * HID + c0] = o0;
      *(float4*)&out[(size_t)v * HID + c0 + 4] = o1;
    }
  }
}

// ---------------- layer-2 aggregate: wave per node, 16-lane groups, 8 gathers in flight ----
__global__ __launch_bounds__(256) void aggregate_kernel(
    const float* __restrict__ h, const int* __restrict__ row_ofs,
    const int* __restrict__ csr_src, const float* __restrict__ ni_,
    float* __restrict__ agg) {
  int v = (blockIdx.x * blockDim.x + threadIdx.x) >> 6;
  int lane = threadIdx.x & 63;
  if (v >= N_NODES) return;
  int beg = row_ofs[v], end = row_ofs[v + 1];
  int g = lane >> 4, l = lane & 15;
  const float4* __restrict__ h4 = (const float4*)h;
  float a0x = 0.f, a0y = 0.f, a0z = 0.f, a0w = 0.f;
  float a1x = 0.f, a1y = 0.f, a1z = 0.f, a1w = 0.f;
  for (int i = beg; i < end; i += 8) {
    int i0 = i + g, i1 = i + 4 + g;
    bool q0 = i0 < end, q1 = i1 < end;
    int s0 = csr_src[q0 ? i0 : beg];
    int s1 = csr_src[q1 ? i1 : beg];
    float m0 = q0 ? 1.f : 0.f, m1 = q1 ? 1.f : 0.f;
    float4 x0 = h4[(size_t)s0 * 32 + l];
    float4 x1 = h4[(size_t)s0 * 32 + 16 + l];
    float4 y0 = h4[(size_t)s1 * 32 + l];
    float4 y1 = h4[(size_t)s1 * 32 + 16 + l];
    a0x += x0.x * m0 + y0.x * m1;
    a0y += x0.y * m0 + y0.y * m1;
    a0z += x0.z * m0 + y0.z * m1;
    a0w += x0.w * m0 + y0.w * m1;
    a1x += x1.x * m0 + y1.x * m1;
    a1y += x1.y * m0 + y1.y * m1;
    a1z += x1.z * m0 + y1.z * m1;
    a1w += x1.w * m0 + y1.w * m1;
  }
  // combine the 4 groups (lanes sharing l across g)
  a0x += __shfl_xor(a0x, 16, 64); a0x += __shfl_xor(a0x, 32, 64);
  a0y += __shfl_xor(a0y, 16, 64); a0y += __shfl_xor(a0y, 32, 64);
  a0z += __shfl_xor(a0z, 16, 64); a0z += __shfl_xor(a0z, 32, 64);
  a0w += __shfl_xor(a0w, 16, 64); a0w += __shfl_xor(a0w, 32, 64);
  a1x += __shfl_xor(a1x, 16, 64); a1x += __shfl_xor(a1x, 32, 64);
  a1y += __shfl_xor(a1y, 16, 64); a1y += __shfl_xor(a1y, 32, 64);
  a1z += __shfl_xor(a1z, 16, 64); a1z += __shfl_xor(a1z, 32, 64);
  a1w += __shfl_xor(a1w, 16, 64); a1w += __shfl_xor(a1w, 32, 64);
  if (g == 0) {
    float n = ni_[v];
    float4* a4 = (float4*)agg;
    a4[(size_t)v * 32 + l] = make_float4(a0x * n, a0y * n, a0z * n, a0w * n);
    a4[(size_t)v * 32 + 16 + l] = make_float4(a1x * n, a1y * n, a1z * n, a1w * n);
  }
}

// ---------------- fused layer-2 GEMM + output GEMM, register micro-tile ----------------
__global__ __launch_bounds__(256) void gemm_dual_kernel(
    const float* __restrict__ in, const float* __restrict__ W0,
    const float* __restrict__ b0, const float* __restrict__ W1,
    float* __restrict__ out, int nrows) {
  __shared__ float As[64 * AP];
  __shared__ float Wbuf[32 * HID];
  int t = threadIdx.x;
  int v0 = blockIdx.x * 64;
  {
    const float4* in4 = (const float4*)in;
#pragma unroll
    for (int i = 0; i < 8; ++i) {
      int idx = i * 256 + t;
      int r = idx >> 5, q = idx & 31;
      int v = v0 + r;
      float4 val = make_float4(0.f, 0.f, 0.f, 0.f);
      if (v < nrows) val = in4[(size_t)v * 32 + q];
      float* p = &As[r * AP + q * 4];
      p[0] = val.x; p[1] = val.y; p[2] = val.z; p[3] = val.w;
    }
  }
  int c0 = (t & 15) * 8, r0 = (t >> 4) * 4;
  float acc[4][8];
#pragma unroll
  for (int i = 0; i < 4; ++i)
#pragma unroll
    for (int j = 0; j < 8; ++j) acc[i][j] = 0.f;

  for (int kc = 0; kc < HID; kc += 32) {
    __syncthreads();
    {
      const float4* wsrc = (const float4*)(W0 + kc * HID);
      float4* wdst = (float4*)Wbuf;
#pragma unroll
      for (int i = 0; i < 4; ++i) wdst[i * 256 + t] = wsrc[i * 256 + t];
    }
    __syncthreads();
#pragma unroll 4
    for (int kk = 0; kk < 32; ++kk) {
      int k = kc + kk;
      float ar[4];
#pragma unroll
      for (int i = 0; i < 4; ++i) ar[i] = As[(r0 + i) * AP + k];
      float4 w0v = *(const float4*)&Wbuf[kk * HID + c0];
      float4 w1v = *(const float4*)&Wbuf[kk * HID + c0 + 4];
      float wv[8] = {w0v.x, w0v.y, w0v.z, w0v.w, w1v.x, w1v.y, w1v.z, w1v.w};
#pragma unroll
      for (int i = 0; i < 4; ++i)
#pragma unroll
        for (int j = 0; j < 8; ++j) acc[i][j] += ar[i] * wv[j];
    }
  }
  __syncthreads();
  {
    float bb[8];
    float4 b0v = *(const float4*)&b0[c0];
    float4 b1v = *(const float4*)&b0[c0 + 4];
    bb[0] = b0v.x; bb[1] = b0v.y; bb[2] = b0v.z; bb[3] = b0v.w;
    bb[4] = b1v.x; bb[5] = b1v.y; bb[6] = b1v.z; bb[7] = b1v.w;
#pragma unroll
    for (int i = 0; i < 4; ++i)
#pragma unroll
      for (int j = 0; j < 8; ++j) {
        As[(r0 + i) * AP + c0 + j] = fmaxf(acc[i][j] + bb[j], 0.f);
        acc[i][j] = 0.f;
      }
  }
  for (int kc = 0; kc < HID; kc += 32) {
    __syncthreads();
    {
      const float4* wsrc = (const float4*)(W1 + kc * HID);
      float4* wdst = (float4*)Wbuf;
#pragma unroll
      for (int i = 0; i < 4; ++i) wdst[i * 256 + t] = wsrc[i * 256 + t];
    }
    __syncthreads();
#pragma unroll 4
    for (int kk = 0; kk < 32; ++kk) {
      int k = kc + kk;
      float ar[4];
#pragma unroll
      for (int i = 0; i < 4; ++i) ar[i] = As[(r0 + i) * AP + k];
      float4 w0v = *(const float4*)&Wbuf[kk * HID + c0];
      float4 w1v = *(const float4*)&Wbuf[kk * HID + c0 + 4];
      float wv[8] = {w0v.x, w0v.y, w0v.z, w0v.w, w1v.x, w1v.y, w1v.z, w1v.w};
#pragma unroll
      for (int i = 0; i < 4; ++i)
#pragma unroll
        for (int j = 0; j < 8; ++j) acc[i][j] += ar[i] * wv[j];
    }
  }
#pragma unroll
  for (int i = 0; i < 4; ++i) {
    int v = v0 + r0 + i;
    if (v < nrows) {
      float4 o0 = make_float4(acc[i][0], acc[i][1], acc[i][2], acc[i][3]);
      float4 o1 = make_float4(acc[i][4], acc[i][5], acc[i][6], acc[i][7]);
      *(float4*)&out[(size_t)v * HID + c0] = o0;
      *(float4*)&out[(size_t)v * HID + c0 + 4] = o1;
    }
  }
}

// ---------------- edge output, dst-grouped, 16 lanes/edge, 2-deep unroll ----------------
__global__ __launch_bounds__(256) void edge_out_kernel(
    const int* __restrict__ csr_src, const int* __restrict__ csr_eid,
    const int* __restrict__ row_ofs, const float* __restrict__ y,
    const float* __restrict__ b1, const float* __restrict__ w2,
    const float* __restrict__ b2, float* __restrict__ out) {
  int v = (blockIdx.x * blockDim.x + threadIdx.x) >> 6;
  int lane = threadIdx.x & 63;
  if (v >= N_NODES) return;
  int beg = row_ofs[v], end = row_ofs[v + 1];
  if (beg >= end) return;
  int g = lane >> 4;
  int l = lane & 15;
  const float4* __restrict__ y4 = (const float4*)y;
  const float4* __restrict__ b14 = (const float4*)b1;
  const float4* __restrict__ w24 = (const float4*)w2;
  float4 d0 = y4[(size_t)v * 32 + l];
  float4 d1 = y4[(size_t)v * 32 + 16 + l];
  float4 bb0 = b14[l], bb1 = b14[16 + l];
  d0.x += bb0.x; d0.y += bb0.y; d0.z += bb0.z; d0.w += bb0.w;
  d1.x += bb1.x; d1.y += bb1.y; d1.z += bb1.z; d1.w += bb1.w;
  float4 w0 = w24[l], w1 = w24[16 + l];
  float ob2 = b2[0];
  for (int i = beg; i < end; i += 8) {
    int i0 = i + g, i1 = i + 4 + g;
    bool q0 = i0 < end, q1 = i1 < end;
    int s0 = csr_src[q0 ? i0 : beg];
    int s1 = csr_src[q1 ? i1 : beg];
    float4 a0 = y4[(size_t)s0 * 32 + l];
    float4 a1 = y4[(size_t)s0 * 32 + 16 + l];
    float4 c0 = y4[(size_t)s1 * 32 + l];
    float4 c1 = y4[(size_t)s1 * 32 + 16 + l];
    float p0 = fmaxf(a0.x + d0.x, 0.f) * w0.x + fmaxf(a0.y + d0.y, 0.f) * w0.y +
               fmaxf(a0.z + d0.z, 0.f) * w0.z + fmaxf(a0.w + d0.w, 0.f) * w0.w +
               fmaxf(a1.x + d1.x, 0.f) * w1.x + fmaxf(a1.y + d1.y, 0.f) * w1.y +
               fmaxf(a1.z + d1.z, 0.f) * w1.z + fmaxf(a1.w + d1.w, 0.f) * w1.w;
    float p1 = fmaxf(c0.x + d0.x, 0.f) * w0.x + fmaxf(c0.y + d0.y, 0.f) * w0.y +
               fmaxf(c0.z + d0.z, 0.f) * w0.z + fmaxf(c0.w + d0.w, 0.f) * w0.w +
               fmaxf(c1.x + d1.x, 0.f) * w1.x + fmaxf(c1.y + d1.y, 0.f) * w1.y +
               fmaxf(c1.z + d1.z, 0.f) * w1.z + fmaxf(c1.w + d1.w, 0.f) * w1.w;
    p0 += __shfl_down(p0, 8, 16);
    p0 += __shfl_down(p0, 4, 16);
    p0 += __shfl_down(p0, 2, 16);
    p0 += __shfl_down(p0, 1, 16);
    p1 += __shfl_down(p1, 8, 16);
    p1 += __shfl_down(p1, 4, 16);
    p1 += __shfl_down(p1, 2, 16);
    p1 += __shfl_down(p1, 1, 16);
    if (l == 0 && q0) out[csr_eid[i0]] = p0 + ob2;
    if (l == 0 && q1) out[csr_eid[i1]] = p1 + ob2;
  }
}

extern "C" void kernel_launch(void* const* d_in, const int* in_sizes, int n_in,
                              void* d_out, int out_size, void* d_ws, size_t ws_size,
                              hipStream_t stream) {
  const float* node_feats = (const float*)d_in[1];
  const int*   src        = (const int*)d_in[2];
  const int*   dst        = (const int*)d_in[3];
  const float* W_nemb     = (const float*)d_in[6];
  const float* b_nemb     = (const float*)d_in[7];
  const float* gnn_W      = (const float*)d_in[8];
  const float* gnn_b      = (const float*)d_in[9];
  const float* out_W1     = (const float*)d_in[10];
  const float* out_b1     = (const float*)d_in[11];
  const float* out_W2     = (const float*)d_in[12];
  const float* out_b2     = (const float*)d_in[13];
  float* out = (float*)d_out;

  size_t off = 0;
  char* base = (char*)d_ws;
  auto alloc = [&](size_t nbytes) -> char* {
    off = (off + 255) & ~(size_t)255;
    char* p = base + off;
    off += nbytes;
    return p;
  };
  int*    cnt_out  = (int*)alloc(N_NODES * 4);
  int*    cnt_in   = (int*)alloc(N_NODES * 4);
  float*  norm_out = (float*)alloc(N_NODES * 4);
  float*  norm_in  = (float*)alloc(N_NODES * 4);
  int*    row_ofs  = (int*)alloc((N_NODES + 1) * 4);
  int*    cursor   = (int*)alloc(N_NODES * 4);
  int*    blk_sums = (int*)alloc(SCAN_BLK * 4);
  int*    blk_base = (int*)alloc(SCAN_BLK * 4);
  int*    csr_src  = (int*)alloc((size_t)N_EDGES * 4);
  int*    csr_eid  = (int*)alloc((size_t)N_EDGES * 4);
  float4* agg4     = (float4*)alloc((size_t)N_NODES * 16);
  float*  sno      = (float*)alloc(N_NODES * 4);
  float*  buf_a    = (float*)alloc((size_t)N_NODES * HID * 4);
  float*  buf_b    = (float*)alloc((size_t)N_NODES * HID * 4);
  (void)ws_size; (void)n_in; (void)in_sizes; (void)out_size;

  const int nb_scan = (N_NODES + SCAN_BLK - 1) / SCAN_BLK;

  hipMemsetAsync(cnt_out, 0, N_NODES * 4, stream);
  hipMemsetAsync(cnt_in, 0, N_NODES * 4, stream);
  deg_kernel<<<(N_EDGES + 255) / 256, 256, 0, stream>>>(src, dst, cnt_out, cnt_in);
  norm_kernel<<<nb_scan, 256, 0, stream>>>(cnt_out, cnt_in, norm_out, norm_in);

  scan_blocks_kernel<<<nb_scan, SCAN_BLK, 0, stream>>>(cnt_in, row_ofs, blk_sums, N_NODES);
  scan_sums_kernel<<<1, SCAN_BLK, 0, stream>>>(blk_sums, blk_base, nb_scan);
  add_base_kernel<<<nb_scan, 256, 0, stream>>>(row_ofs, blk_base, cursor, N_NODES, N_EDGES);
  csr_fill_kernel<<<(N_EDGES + 255) / 256, 256, 0, stream>>>(src, dst, cursor, csr_src, csr_eid);

  agg4_kernel<<<(N_NODES * 16 + 255) / 256, 256, 0, stream>>>(
      (const float4*)node_feats, norm_out, csr_src, row_ofs, agg4, sno);
  gemm_l1_kernel<<<(N_NODES + 63) / 64, 256, 0, stream>>>(
      agg4, sno, norm_in, norm_out, W_nemb, b_nemb, gnn_W, gnn_b, buf_a, N_NODES);

  aggregate_kernel<<<(N_NODES * 64 + 255) / 256, 256, 0, stream>>>(
      buf_a, row_ofs, csr_src, norm_in, buf_b);

  gemm_dual_kernel<<<(N_NODES + 63) / 64, 256, 0, stream>>>(
      buf_b, gnn_W + (size_t)HID * HID, gnn_b + HID, out_W1, buf_a, N_NODES);

  edge_out_kernel<<<(N_NODES * 64 + 255) / 256, 256, 0, stream>>>(
      csr_src, csr_eid, row_ofs, buf_a, out_b1, out_W2, out_b2, out);
}

// Round 5
// 448.962 us; speedup vs baseline: 1.5741x; 1.0182x over previous
//
#include <hip/hip_runtime.h>

#define N_NODES 50000
#define N_EDGES 800000
#define HID 128
#define SCAN_BLK 256
#define AP 133   // padded row stride for As (bank-spread: 133%32=5)

// ---------------- degrees ----------------
__global__ void deg_kernel(const int* __restrict__ src, const int* __restrict__ dst,
                           int* __restrict__ cnt_out, int* __restrict__ cnt_in) {
  int e = blockIdx.x * blockDim.x + threadIdx.x;
  if (e < N_EDGES) {
    atomicAdd(&cnt_out[src[e]], 1);
    atomicAdd(&cnt_in[dst[e]], 1);
  }
}

__global__ void norm_kernel(const int* __restrict__ cnt_out, const int* __restrict__ cnt_in,
                            float* __restrict__ norm_out, float* __restrict__ norm_in) {
  int v = blockIdx.x * blockDim.x + threadIdx.x;
  if (v < N_NODES) {
    int co = cnt_out[v]; if (co < 1) co = 1;
    int ci = cnt_in[v];  if (ci < 1) ci = 1;
    norm_out[v] = rsqrtf((float)co);
    norm_in[v]  = rsqrtf((float)ci);
  }
}

// ---------------- CSR build ----------------
__global__ void scan_blocks_kernel(const int* __restrict__ cnt, int* __restrict__ ofs,
                                   int* __restrict__ blk_sums, int n) {
  __shared__ int s[SCAN_BLK];
  int t = threadIdx.x;
  int i = blockIdx.x * SCAN_BLK + t;
  int v = (i < n) ? cnt[i] : 0;
  s[t] = v;
  __syncthreads();
  for (int o = 1; o < SCAN_BLK; o <<= 1) {
    int x = (t >= o) ? s[t - o] : 0;
    __syncthreads();
    s[t] += x;
    __syncthreads();
  }
  if (i < n) ofs[i] = s[t] - v;
  if (t == SCAN_BLK - 1) blk_sums[blockIdx.x] = s[t];
}

__global__ void scan_sums_kernel(const int* __restrict__ blk_sums, int* __restrict__ blk_base,
                                 int nb) {
  __shared__ int s[SCAN_BLK];
  int t = threadIdx.x;
  int v = (t < nb) ? blk_sums[t] : 0;
  s[t] = v;
  __syncthreads();
  for (int o = 1; o < SCAN_BLK; o <<= 1) {
    int x = (t >= o) ? s[t - o] : 0;
    __syncthreads();
    s[t] += x;
    __syncthreads();
  }
  if (t < nb) blk_base[t] = s[t] - v;
}

__global__ void add_base_kernel(int* __restrict__ ofs, const int* __restrict__ blk_base,
                                int* __restrict__ cursor, int n, int total) {
  int i = blockIdx.x * blockDim.x + threadIdx.x;
  if (i < n) {
    int r = ofs[i] + blk_base[i >> 8];
    ofs[i] = r;
    cursor[i] = r;
  }
  if (i == 0) ofs[n] = total;
}

__global__ void csr_fill_kernel(const int* __restrict__ src, const int* __restrict__ dst,
                                int* __restrict__ cursor, int* __restrict__ csr_src,
                                int* __restrict__ csr_eid) {
  int e = blockIdx.x * blockDim.x + threadIdx.x;
  if (e < N_EDGES) {
    int p = atomicAdd(&cursor[dst[e]], 1);
    csr_src[p] = src[e];
    csr_eid[p] = e;
  }
}

// ---------------- layer-1 aggregate on RAW 4-dim features ----------------
__global__ __launch_bounds__(256) void agg4_kernel(
    const float4* __restrict__ nf4, const float* __restrict__ no_,
    const int* __restrict__ csr_src, const int* __restrict__ row_ofs,
    float4* __restrict__ agg4, float* __restrict__ sno) {
  int wid = (blockIdx.x * blockDim.x + threadIdx.x) >> 6;
  int lane = threadIdx.x & 63;
  int g = lane >> 4, l = lane & 15;
  int v = wid * 4 + g;
  if (v >= N_NODES) return;
  int beg = row_ofs[v], end = row_ofs[v + 1];
  float ax = 0.f, ay = 0.f, az = 0.f, aw = 0.f, sn = 0.f;
  for (int i = beg + l; i < end; i += 16) {
    int s = csr_src[i];
    float w = no_[s];
    float4 n = nf4[s];
    ax += n.x * w; ay += n.y * w; az += n.z * w; aw += n.w * w;
    sn += w;
  }
#pragma unroll
  for (int o = 1; o < 16; o <<= 1) {
    ax += __shfl_xor(ax, o, 16);
    ay += __shfl_xor(ay, o, 16);
    az += __shfl_xor(az, o, 16);
    aw += __shfl_xor(aw, o, 16);
    sn += __shfl_xor(sn, o, 16);
  }
  if (l == 0) {
    agg4[v] = make_float4(ax, ay, az, aw);
    sno[v] = sn;
  }
}

// ---------------- layer-1: fused 4->128 expand + GEMM, register micro-tile ----------------
// mapping: c0=(t>>4)*8 (4 col-groups/wave, Wbuf b128 broadcast, conflict-free)
//          r0=(t&15)*4 (16 row-groups/wave, At b128 2-way = free)
__global__ __launch_bounds__(256) void gemm_l1_kernel(
    const float4* __restrict__ agg4, const float* __restrict__ sno,
    const float* __restrict__ ni_, const float* __restrict__ no_,
    const float* __restrict__ Wn, const float* __restrict__ bn,
    const float* __restrict__ W0, const float* __restrict__ b0,
    float* __restrict__ out, int nrows) {
  __shared__ float At[HID * 64];      // 32 KB, k-major
  __shared__ float Wbuf[32 * HID];    // 16 KB
  int t = threadIdx.x;
  int v0 = blockIdx.x * 64;
  {
    int r = t & 63, kg = t >> 6;
    int v = v0 + r;
    float4 a = make_float4(0.f, 0.f, 0.f, 0.f);
    float sn = 0.f, nin = 0.f;
    if (v < nrows) { a = agg4[v]; sn = sno[v]; nin = ni_[v]; }
    for (int kk = 0; kk < 32; ++kk) {
      int k = kg * 32 + kk;  // wave-uniform
      float val = (a.x * Wn[k] + a.y * Wn[HID + k] + a.z * Wn[2 * HID + k] +
                   a.w * Wn[3 * HID + k] + bn[k] * sn) * nin;
      At[k * 64 + r] = val;
    }
  }
  int c0 = (t >> 4) * 8, r0 = (t & 15) * 4;
  float acc[4][8];
#pragma unroll
  for (int i = 0; i < 4; ++i)
#pragma unroll
    for (int j = 0; j < 8; ++j) acc[i][j] = 0.f;

  for (int kc = 0; kc < HID; kc += 32) {
    __syncthreads();
    {
      const float4* wsrc = (const float4*)(W0 + kc * HID);
      float4* wdst = (float4*)Wbuf;
#pragma unroll
      for (int i = 0; i < 4; ++i) wdst[i * 256 + t] = wsrc[i * 256 + t];
    }
    __syncthreads();
#pragma unroll 4
    for (int kk = 0; kk < 32; ++kk) {
      float4 av = *(const float4*)&At[(kc + kk) * 64 + r0];
      float4 w0v = *(const float4*)&Wbuf[kk * HID + c0];
      float4 w1v = *(const float4*)&Wbuf[kk * HID + c0 + 4];
      float ar[4] = {av.x, av.y, av.z, av.w};
      float wv[8] = {w0v.x, w0v.y, w0v.z, w0v.w, w1v.x, w1v.y, w1v.z, w1v.w};
#pragma unroll
      for (int i = 0; i < 4; ++i)
#pragma unroll
        for (int j = 0; j < 8; ++j) acc[i][j] += ar[i] * wv[j];
    }
  }
  float bb[8];
  {
    float4 b0v = *(const float4*)&b0[c0];
    float4 b1v = *(const float4*)&b0[c0 + 4];
    bb[0] = b0v.x; bb[1] = b0v.y; bb[2] = b0v.z; bb[3] = b0v.w;
    bb[4] = b1v.x; bb[5] = b1v.y; bb[6] = b1v.z; bb[7] = b1v.w;
  }
#pragma unroll
  for (int i = 0; i < 4; ++i) {
    int v = v0 + r0 + i;
    if (v < nrows) {
      float nov = no_[v];
      float4 o0, o1;
      o0.x = fmaxf(acc[i][0] + bb[0], 0.f) * nov;
      o0.y = fmaxf(acc[i][1] + bb[1], 0.f) * nov;
      o0.z = fmaxf(acc[i][2] + bb[2], 0.f) * nov;
      o0.w = fmaxf(acc[i][3] + bb[3], 0.f) * nov;
      o1.x = fmaxf(acc[i][4] + bb[4], 0.f) * nov;
      o1.y = fmaxf(acc[i][5] + bb[5], 0.f) * nov;
      o1.z = fmaxf(acc[i][6] + bb[6], 0.f) * nov;
      o1.w = fmaxf(acc[i][7] + bb[7], 0.f) * nov;
      *(float4*)&out[(size_t)v * HID + c0] = o0;
      *(float4*)&out[(size_t)v * HID + c0 + 4] = o1;
    }
  }
}

// ---------------- layer-2 aggregate: wave per node, 16-lane groups ----------------
__global__ __launch_bounds__(256) void aggregate_kernel(
    const float* __restrict__ h, const int* __restrict__ row_ofs,
    const int* __restrict__ csr_src, const float* __restrict__ ni_,
    float* __restrict__ agg) {
  int v = (blockIdx.x * blockDim.x + threadIdx.x) >> 6;
  int lane = threadIdx.x & 63;
  if (v >= N_NODES) return;
  int beg = row_ofs[v], end = row_ofs[v + 1];
  int g = lane >> 4, l = lane & 15;
  const float4* __restrict__ h4 = (const float4*)h;
  float a0x = 0.f, a0y = 0.f, a0z = 0.f, a0w = 0.f;
  float a1x = 0.f, a1y = 0.f, a1z = 0.f, a1w = 0.f;
  for (int i = beg; i < end; i += 8) {
    int i0 = i + g, i1 = i + 4 + g;
    bool q0 = i0 < end, q1 = i1 < end;
    int s0 = csr_src[q0 ? i0 : beg];
    int s1 = csr_src[q1 ? i1 : beg];
    float m0 = q0 ? 1.f : 0.f, m1 = q1 ? 1.f : 0.f;
    float4 x0 = h4[(size_t)s0 * 32 + l];
    float4 x1 = h4[(size_t)s0 * 32 + 16 + l];
    float4 y0 = h4[(size_t)s1 * 32 + l];
    float4 y1 = h4[(size_t)s1 * 32 + 16 + l];
    a0x += x0.x * m0 + y0.x * m1;
    a0y += x0.y * m0 + y0.y * m1;
    a0z += x0.z * m0 + y0.z * m1;
    a0w += x0.w * m0 + y0.w * m1;
    a1x += x1.x * m0 + y1.x * m1;
    a1y += x1.y * m0 + y1.y * m1;
    a1z += x1.z * m0 + y1.z * m1;
    a1w += x1.w * m0 + y1.w * m1;
  }
  a0x += __shfl_xor(a0x, 16, 64); a0x += __shfl_xor(a0x, 32, 64);
  a0y += __shfl_xor(a0y, 16, 64); a0y += __shfl_xor(a0y, 32, 64);
  a0z += __shfl_xor(a0z, 16, 64); a0z += __shfl_xor(a0z, 32, 64);
  a0w += __shfl_xor(a0w, 16, 64); a0w += __shfl_xor(a0w, 32, 64);
  a1x += __shfl_xor(a1x, 16, 64); a1x += __shfl_xor(a1x, 32, 64);
  a1y += __shfl_xor(a1y, 16, 64); a1y += __shfl_xor(a1y, 32, 64);
  a1z += __shfl_xor(a1z, 16, 64); a1z += __shfl_xor(a1z, 32, 64);
  a1w += __shfl_xor(a1w, 16, 64); a1w += __shfl_xor(a1w, 32, 64);
  if (g == 0) {
    float n = ni_[v];
    float4* a4 = (float4*)agg;
    a4[(size_t)v * 32 + l] = make_float4(a0x * n, a0y * n, a0z * n, a0w * n);
    a4[(size_t)v * 32 + 16 + l] = make_float4(a1x * n, a1y * n, a1z * n, a1w * n);
  }
}

// ---------------- fused layer-2 GEMM + output GEMM, register micro-tile ----------------
// same conflict-free mapping: c0=(t>>4)*8, r0=(t&15)*4
__global__ __launch_bounds__(256) void gemm_dual_kernel(
    const float* __restrict__ in, const float* __restrict__ W0,
    const float* __restrict__ b0, const float* __restrict__ W1,
    float* __restrict__ out, int nrows) {
  __shared__ float As[64 * AP];
  __shared__ float Wbuf[32 * HID];
  int t = threadIdx.x;
  int v0 = blockIdx.x * 64;
  {
    const float4* in4 = (const float4*)in;
#pragma unroll
    for (int i = 0; i < 8; ++i) {
      int idx = i * 256 + t;
      int r = idx >> 5, q = idx & 31;
      int v = v0 + r;
      float4 val = make_float4(0.f, 0.f, 0.f, 0.f);
      if (v < nrows) val = in4[(size_t)v * 32 + q];
      float* p = &As[r * AP + q * 4];
      p[0] = val.x; p[1] = val.y; p[2] = val.z; p[3] = val.w;
    }
  }
  int c0 = (t >> 4) * 8, r0 = (t & 15) * 4;
  float acc[4][8];
#pragma unroll
  for (int i = 0; i < 4; ++i)
#pragma unroll
    for (int j = 0; j < 8; ++j) acc[i][j] = 0.f;

  for (int kc = 0; kc < HID; kc += 32) {
    __syncthreads();
    {
      const float4* wsrc = (const float4*)(W0 + kc * HID);
      float4* wdst = (float4*)Wbuf;
#pragma unroll
      for (int i = 0; i < 4; ++i) wdst[i * 256 + t] = wsrc[i * 256 + t];
    }
    __syncthreads();
#pragma unroll 4
    for (int kk = 0; kk < 32; ++kk) {
      int k = kc + kk;
      float ar[4];
#pragma unroll
      for (int i = 0; i < 4; ++i) ar[i] = As[(r0 + i) * AP + k];
      float4 w0v = *(const float4*)&Wbuf[kk * HID + c0];
      float4 w1v = *(const float4*)&Wbuf[kk * HID + c0 + 4];
      float wv[8] = {w0v.x, w0v.y, w0v.z, w0v.w, w1v.x, w1v.y, w1v.z, w1v.w};
#pragma unroll
      for (int i = 0; i < 4; ++i)
#pragma unroll
        for (int j = 0; j < 8; ++j) acc[i][j] += ar[i] * wv[j];
    }
  }
  __syncthreads();
  {
    float bb[8];
    float4 b0v = *(const float4*)&b0[c0];
    float4 b1v = *(const float4*)&b0[c0 + 4];
    bb[0] = b0v.x; bb[1] = b0v.y; bb[2] = b0v.z; bb[3] = b0v.w;
    bb[4] = b1v.x; bb[5] = b1v.y; bb[6] = b1v.z; bb[7] = b1v.w;
#pragma unroll
    for (int i = 0; i < 4; ++i)
#pragma unroll
      for (int j = 0; j < 8; ++j) {
        As[(r0 + i) * AP + c0 + j] = fmaxf(acc[i][j] + bb[j], 0.f);
        acc[i][j] = 0.f;
      }
  }
  for (int kc = 0; kc < HID; kc += 32) {
    __syncthreads();
    {
      const float4* wsrc = (const float4*)(W1 + kc * HID);
      float4* wdst = (float4*)Wbuf;
#pragma unroll
      for (int i = 0; i < 4; ++i) wdst[i * 256 + t] = wsrc[i * 256 + t];
    }
    __syncthreads();
#pragma unroll 4
    for (int kk = 0; kk < 32; ++kk) {
      int k = kc + kk;
      float ar[4];
#pragma unroll
      for (int i = 0; i < 4; ++i) ar[i] = As[(r0 + i) * AP + k];
      float4 w0v = *(const float4*)&Wbuf[kk * HID + c0];
      float4 w1v = *(const float4*)&Wbuf[kk * HID + c0 + 4];
      float wv[8] = {w0v.x, w0v.y, w0v.z, w0v.w, w1v.x, w1v.y, w1v.z, w1v.w};
#pragma unroll
      for (int i = 0; i < 4; ++i)
#pragma unroll
        for (int j = 0; j < 8; ++j) acc[i][j] += ar[i] * wv[j];
    }
  }
#pragma unroll
  for (int i = 0; i < 4; ++i) {
    int v = v0 + r0 + i;
    if (v < nrows) {
      float4 o0 = make_float4(acc[i][0], acc[i][1], acc[i][2], acc[i][3]);
      float4 o1 = make_float4(acc[i][4], acc[i][5], acc[i][6], acc[i][7]);
      *(float4*)&out[(size_t)v * HID + c0] = o0;
      *(float4*)&out[(size_t)v * HID + c0 + 4] = o1;
    }
  }
}

// ---------------- edge output, dst-grouped, 16 lanes/edge, 2-deep unroll ----------------
__global__ __launch_bounds__(256) void edge_out_kernel(
    const int* __restrict__ csr_src, const int* __restrict__ csr_eid,
    const int* __restrict__ row_ofs, const float* __restrict__ y,
    const float* __restrict__ b1, const float* __restrict__ w2,
    const float* __restrict__ b2, float* __restrict__ out) {
  int v = (blockIdx.x * blockDim.x + threadIdx.x) >> 6;
  int lane = threadIdx.x & 63;
  if (v >= N_NODES) return;
  int beg = row_ofs[v], end = row_ofs[v + 1];
  if (beg >= end) return;
  int g = lane >> 4;
  int l = lane & 15;
  const float4* __restrict__ y4 = (const float4*)y;
  const float4* __restrict__ b14 = (const float4*)b1;
  const float4* __restrict__ w24 = (const float4*)w2;
  float4 d0 = y4[(size_t)v * 32 + l];
  float4 d1 = y4[(size_t)v * 32 + 16 + l];
  float4 bb0 = b14[l], bb1 = b14[16 + l];
  d0.x += bb0.x; d0.y += bb0.y; d0.z += bb0.z; d0.w += bb0.w;
  d1.x += bb1.x; d1.y += bb1.y; d1.z += bb1.z; d1.w += bb1.w;
  float4 w0 = w24[l], w1 = w24[16 + l];
  float ob2 = b2[0];
  for (int i = beg; i < end; i += 8) {
    int i0 = i + g, i1 = i + 4 + g;
    bool q0 = i0 < end, q1 = i1 < end;
    int s0 = csr_src[q0 ? i0 : beg];
    int s1 = csr_src[q1 ? i1 : beg];
    float4 a0 = y4[(size_t)s0 * 32 + l];
    float4 a1 = y4[(size_t)s0 * 32 + 16 + l];
    float4 c0 = y4[(size_t)s1 * 32 + l];
    float4 c1 = y4[(size_t)s1 * 32 + 16 + l];
    float p0 = fmaxf(a0.x + d0.x, 0.f) * w0.x + fmaxf(a0.y + d0.y, 0.f) * w0.y +
               fmaxf(a0.z + d0.z, 0.f) * w0.z + fmaxf(a0.w + d0.w, 0.f) * w0.w +
               fmaxf(a1.x + d1.x, 0.f) * w1.x + fmaxf(a1.y + d1.y, 0.f) * w1.y +
               fmaxf(a1.z + d1.z, 0.f) * w1.z + fmaxf(a1.w + d1.w, 0.f) * w1.w;
    float p1 = fmaxf(c0.x + d0.x, 0.f) * w0.x + fmaxf(c0.y + d0.y, 0.f) * w0.y +
               fmaxf(c0.z + d0.z, 0.f) * w0.z + fmaxf(c0.w + d0.w, 0.f) * w0.w +
               fmaxf(c1.x + d1.x, 0.f) * w1.x + fmaxf(c1.y + d1.y, 0.f) * w1.y +
               fmaxf(c1.z + d1.z, 0.f) * w1.z + fmaxf(c1.w + d1.w, 0.f) * w1.w;
    p0 += __shfl_down(p0, 8, 16);
    p0 += __shfl_down(p0, 4, 16);
    p0 += __shfl_down(p0, 2, 16);
    p0 += __shfl_down(p0, 1, 16);
    p1 += __shfl_down(p1, 8, 16);
    p1 += __shfl_down(p1, 4, 16);
    p1 += __shfl_down(p1, 2, 16);
    p1 += __shfl_down(p1, 1, 16);
    if (l == 0 && q0) out[csr_eid[i0]] = p0 + ob2;
    if (l == 0 && q1) out[csr_eid[i1]] = p1 + ob2;
  }
}

extern "C" void kernel_launch(void* const* d_in, const int* in_sizes, int n_in,
                              void* d_out, int out_size, void* d_ws, size_t ws_size,
                              hipStream_t stream) {
  const float* node_feats = (const float*)d_in[1];
  const int*   src        = (const int*)d_in[2];
  const int*   dst        = (const int*)d_in[3];
  const float* W_nemb     = (const float*)d_in[6];
  const float* b_nemb     = (const float*)d_in[7];
  const float* gnn_W      = (const float*)d_in[8];
  const float* gnn_b      = (const float*)d_in[9];
  const float* out_W1     = (const float*)d_in[10];
  const float* out_b1     = (const float*)d_in[11];
  const float* out_W2     = (const float*)d_in[12];
  const float* out_b2     = (const float*)d_in[13];
  float* out = (float*)d_out;

  size_t off = 0;
  char* base = (char*)d_ws;
  auto alloc = [&](size_t nbytes) -> char* {
    off = (off + 255) & ~(size_t)255;
    char* p = base + off;
    off += nbytes;
    return p;
  };
  int*    cnt_out  = (int*)alloc(N_NODES * 4);
  int*    cnt_in   = (int*)alloc(N_NODES * 4);
  float*  norm_out = (float*)alloc(N_NODES * 4);
  float*  norm_in  = (float*)alloc(N_NODES * 4);
  int*    row_ofs  = (int*)alloc((N_NODES + 1) * 4);
  int*    cursor   = (int*)alloc(N_NODES * 4);
  int*    blk_sums = (int*)alloc(SCAN_BLK * 4);
  int*    blk_base = (int*)alloc(SCAN_BLK * 4);
  int*    csr_src  = (int*)alloc((size_t)N_EDGES * 4);
  int*    csr_eid  = (int*)alloc((size_t)N_EDGES * 4);
  float4* agg4     = (float4*)alloc((size_t)N_NODES * 16);
  float*  sno      = (float*)alloc(N_NODES * 4);
  float*  buf_a    = (float*)alloc((size_t)N_NODES * HID * 4);
  float*  buf_b    = (float*)alloc((size_t)N_NODES * HID * 4);
  (void)ws_size; (void)n_in; (void)in_sizes; (void)out_size;

  const int nb_scan = (N_NODES + SCAN_BLK - 1) / SCAN_BLK;

  hipMemsetAsync(cnt_out, 0, N_NODES * 4, stream);
  hipMemsetAsync(cnt_in, 0, N_NODES * 4, stream);
  deg_kernel<<<(N_EDGES + 255) / 256, 256, 0, stream>>>(src, dst, cnt_out, cnt_in);
  norm_kernel<<<nb_scan, 256, 0, stream>>>(cnt_out, cnt_in, norm_out, norm_in);

  scan_blocks_kernel<<<nb_scan, SCAN_BLK, 0, stream>>>(cnt_in, row_ofs, blk_sums, N_NODES);
  scan_sums_kernel<<<1, SCAN_BLK, 0, stream>>>(blk_sums, blk_base, nb_scan);
  add_base_kernel<<<nb_scan, 256, 0, stream>>>(row_ofs, blk_base, cursor, N_NODES, N_EDGES);
  csr_fill_kernel<<<(N_EDGES + 255) / 256, 256, 0, stream>>>(src, dst, cursor, csr_src, csr_eid);

  agg4_kernel<<<(N_NODES * 16 + 255) / 256, 256, 0, stream>>>(
      (const float4*)node_feats, norm_out, csr_src, row_ofs, agg4, sno);
  gemm_l1_kernel<<<(N_NODES + 63) / 64, 256, 0, stream>>>(
      agg4, sno, norm_in, norm_out, W_nemb, b_nemb, gnn_W, gnn_b, buf_a, N_NODES);

  aggregate_kernel<<<(N_NODES * 64 + 255) / 256, 256, 0, stream>>>(
      buf_a, row_ofs, csr_src, norm_in, buf_b);

  gemm_dual_kernel<<<(N_NODES + 63) / 64, 256, 0, stream>>>(
      buf_b, gnn_W + (size_t)HID * HID, gnn_b + HID, out_W1, buf_a, N_NODES);

  edge_out_kernel<<<(N_NODES * 64 + 255) / 256, 256, 0, stream>>>(
      csr_src, csr_eid, row_ofs, buf_a, out_b1, out_W2, out_b2, out);
}